// Round 1
// baseline (2235.203 us; speedup 1.0000x reference)
//
#include <hip/hip_runtime.h>
#include <hip/hip_bf16.h>

typedef unsigned short u16;

#define Bb 4
#define Tt 2048
#define Cc 1024
#define Hh 16
#define C3 3072
#define Mm 8192

__device__ __forceinline__ float bf2f(u16 u) {
    return __uint_as_float(((unsigned int)u) << 16);
}
__device__ __forceinline__ u16 f2bf(float f) {
    unsigned int x = __float_as_uint(f);
    return (u16)((x + 0x7fffu + ((x >> 16) & 1u)) >> 16);
}

// ---------------- GEMM1: qkv = x(f32) @ Wqkv(f32) -> bf16 ----------------
__global__ __launch_bounds__(256) void gemm_xqkv(const float* __restrict__ A,
                                                 const float* __restrict__ Bw,
                                                 u16* __restrict__ Cq,
                                                 int N, int K) {
    __shared__ float As[16][68];
    __shared__ float Bs[16][68];
    const int tid = threadIdx.x;
    const int tx = tid & 15, ty = tid >> 4;
    const int bm = blockIdx.x * 64, bn = blockIdx.y * 64;
    const int lm = tid >> 2, lkq = (tid & 3) << 2;   // A-load: row, k-quad
    const int lk = tid >> 4, lnq = (tid & 15) << 2;  // B-load: k, n-quad
    float acc[4][4] = {};
    for (int k0 = 0; k0 < K; k0 += 16) {
        float4 av = *reinterpret_cast<const float4*>(A + (size_t)(bm + lm) * K + k0 + lkq);
        float4 bv = *reinterpret_cast<const float4*>(Bw + (size_t)(k0 + lk) * N + bn + lnq);
        As[lkq + 0][lm] = av.x; As[lkq + 1][lm] = av.y;
        As[lkq + 2][lm] = av.z; As[lkq + 3][lm] = av.w;
        *reinterpret_cast<float4*>(&Bs[lk][lnq]) = bv;
        __syncthreads();
#pragma unroll
        for (int k = 0; k < 16; ++k) {
            float a0 = As[k][ty * 4 + 0], a1 = As[k][ty * 4 + 1];
            float a2 = As[k][ty * 4 + 2], a3 = As[k][ty * 4 + 3];
            float b0 = Bs[k][tx * 4 + 0], b1 = Bs[k][tx * 4 + 1];
            float b2 = Bs[k][tx * 4 + 2], b3 = Bs[k][tx * 4 + 3];
            acc[0][0] = fmaf(a0, b0, acc[0][0]); acc[0][1] = fmaf(a0, b1, acc[0][1]);
            acc[0][2] = fmaf(a0, b2, acc[0][2]); acc[0][3] = fmaf(a0, b3, acc[0][3]);
            acc[1][0] = fmaf(a1, b0, acc[1][0]); acc[1][1] = fmaf(a1, b1, acc[1][1]);
            acc[1][2] = fmaf(a1, b2, acc[1][2]); acc[1][3] = fmaf(a1, b3, acc[1][3]);
            acc[2][0] = fmaf(a2, b0, acc[2][0]); acc[2][1] = fmaf(a2, b1, acc[2][1]);
            acc[2][2] = fmaf(a2, b2, acc[2][2]); acc[2][3] = fmaf(a2, b3, acc[2][3]);
            acc[3][0] = fmaf(a3, b0, acc[3][0]); acc[3][1] = fmaf(a3, b1, acc[3][1]);
            acc[3][2] = fmaf(a3, b2, acc[3][2]); acc[3][3] = fmaf(a3, b3, acc[3][3]);
        }
        __syncthreads();
    }
#pragma unroll
    for (int i = 0; i < 4; ++i) {
        int m = bm + ty * 4 + i;
        ushort4 pk;
        pk.x = f2bf(acc[i][0]); pk.y = f2bf(acc[i][1]);
        pk.z = f2bf(acc[i][2]); pk.w = f2bf(acc[i][3]);
        *reinterpret_cast<ushort4*>(Cq + (size_t)m * N + bn + tx * 4) = pk;
    }
}

// ---------------- GEMM2: out = y(bf16) @ Wout(f32) -> f32 ----------------
__global__ __launch_bounds__(256) void gemm_yout(const u16* __restrict__ A,
                                                 const float* __restrict__ Bw,
                                                 float* __restrict__ Co,
                                                 int N, int K) {
    __shared__ float As[16][68];
    __shared__ float Bs[16][68];
    const int tid = threadIdx.x;
    const int tx = tid & 15, ty = tid >> 4;
    const int bm = blockIdx.x * 64, bn = blockIdx.y * 64;
    const int lm = tid >> 2, lkq = (tid & 3) << 2;
    const int lk = tid >> 4, lnq = (tid & 15) << 2;
    float acc[4][4] = {};
    for (int k0 = 0; k0 < K; k0 += 16) {
        ushort4 av = *reinterpret_cast<const ushort4*>(A + (size_t)(bm + lm) * K + k0 + lkq);
        float4 bv = *reinterpret_cast<const float4*>(Bw + (size_t)(k0 + lk) * N + bn + lnq);
        As[lkq + 0][lm] = bf2f(av.x); As[lkq + 1][lm] = bf2f(av.y);
        As[lkq + 2][lm] = bf2f(av.z); As[lkq + 3][lm] = bf2f(av.w);
        *reinterpret_cast<float4*>(&Bs[lk][lnq]) = bv;
        __syncthreads();
#pragma unroll
        for (int k = 0; k < 16; ++k) {
            float a0 = As[k][ty * 4 + 0], a1 = As[k][ty * 4 + 1];
            float a2 = As[k][ty * 4 + 2], a3 = As[k][ty * 4 + 3];
            float b0 = Bs[k][tx * 4 + 0], b1 = Bs[k][tx * 4 + 1];
            float b2 = Bs[k][tx * 4 + 2], b3 = Bs[k][tx * 4 + 3];
            acc[0][0] = fmaf(a0, b0, acc[0][0]); acc[0][1] = fmaf(a0, b1, acc[0][1]);
            acc[0][2] = fmaf(a0, b2, acc[0][2]); acc[0][3] = fmaf(a0, b3, acc[0][3]);
            acc[1][0] = fmaf(a1, b0, acc[1][0]); acc[1][1] = fmaf(a1, b1, acc[1][1]);
            acc[1][2] = fmaf(a1, b2, acc[1][2]); acc[1][3] = fmaf(a1, b3, acc[1][3]);
            acc[2][0] = fmaf(a2, b0, acc[2][0]); acc[2][1] = fmaf(a2, b1, acc[2][1]);
            acc[2][2] = fmaf(a2, b2, acc[2][2]); acc[2][3] = fmaf(a2, b3, acc[2][3]);
            acc[3][0] = fmaf(a3, b0, acc[3][0]); acc[3][1] = fmaf(a3, b1, acc[3][1]);
            acc[3][2] = fmaf(a3, b2, acc[3][2]); acc[3][3] = fmaf(a3, b3, acc[3][3]);
        }
        __syncthreads();
    }
#pragma unroll
    for (int i = 0; i < 4; ++i) {
        int m = bm + ty * 4 + i;
        float4 ov = make_float4(acc[i][0], acc[i][1], acc[i][2], acc[i][3]);
        *reinterpret_cast<float4*>(Co + (size_t)m * N + bn + tx * 4) = ov;
    }
}

// ---------------- Flash attention (causal), fp32 compute ----------------
// 1 thread = 1 query row. Block = 256 threads = 256 query rows of one (b,h).
__global__ __launch_bounds__(256) void attn_flash(const u16* __restrict__ qkv,
                                                  u16* __restrict__ y) {
    __shared__ float Kl[64][68];
    __shared__ float Vl[64][68];
    const int tid = threadIdx.x;
    const int gid = blockIdx.x;
    const int qb = gid & 7;          // T/256 = 8 query chunks
    const int h  = (gid >> 3) & 15;
    const int b  = gid >> 7;
    const int qi = qb * 256 + tid;

    float q[64];
    {
        const u16* qp = qkv + ((size_t)(b * Tt + qi) * C3 + h * 64);
#pragma unroll
        for (int s = 0; s < 8; ++s) {
            uint4 u = *reinterpret_cast<const uint4*>(qp + s * 8);
            q[s * 8 + 0] = bf2f((u16)(u.x & 0xffffu)); q[s * 8 + 1] = bf2f((u16)(u.x >> 16));
            q[s * 8 + 2] = bf2f((u16)(u.y & 0xffffu)); q[s * 8 + 3] = bf2f((u16)(u.y >> 16));
            q[s * 8 + 4] = bf2f((u16)(u.z & 0xffffu)); q[s * 8 + 5] = bf2f((u16)(u.z >> 16));
            q[s * 8 + 6] = bf2f((u16)(u.w & 0xffffu)); q[s * 8 + 7] = bf2f((u16)(u.w >> 16));
        }
#pragma unroll
        for (int dd = 0; dd < 64; ++dd) q[dd] *= 0.125f;  // 1/sqrt(64)
    }

    float mrun = -1e30f, lrun = 0.f;
    float acc[64];
#pragma unroll
    for (int dd = 0; dd < 64; ++dd) acc[dd] = 0.f;

    const int ktiles = qb * 4 + 4;
    const int lrow = tid >> 2, lseg = (tid & 3) * 16;
    for (int kt = 0; kt < ktiles; ++kt) {
        size_t base = (size_t)(b * Tt + kt * 64 + lrow) * C3 + h * 64 + lseg;
        const u16* kp = qkv + base + 1024;
        const u16* vp = qkv + base + 2048;
#pragma unroll
        for (int s = 0; s < 2; ++s) {
            uint4 uk = *reinterpret_cast<const uint4*>(kp + s * 8);
            uint4 uv = *reinterpret_cast<const uint4*>(vp + s * 8);
            int c = lseg + s * 8;
            Kl[lrow][c + 0] = bf2f((u16)(uk.x & 0xffffu)); Kl[lrow][c + 1] = bf2f((u16)(uk.x >> 16));
            Kl[lrow][c + 2] = bf2f((u16)(uk.y & 0xffffu)); Kl[lrow][c + 3] = bf2f((u16)(uk.y >> 16));
            Kl[lrow][c + 4] = bf2f((u16)(uk.z & 0xffffu)); Kl[lrow][c + 5] = bf2f((u16)(uk.z >> 16));
            Kl[lrow][c + 6] = bf2f((u16)(uk.w & 0xffffu)); Kl[lrow][c + 7] = bf2f((u16)(uk.w >> 16));
            Vl[lrow][c + 0] = bf2f((u16)(uv.x & 0xffffu)); Vl[lrow][c + 1] = bf2f((u16)(uv.x >> 16));
            Vl[lrow][c + 2] = bf2f((u16)(uv.y & 0xffffu)); Vl[lrow][c + 3] = bf2f((u16)(uv.y >> 16));
            Vl[lrow][c + 4] = bf2f((u16)(uv.z & 0xffffu)); Vl[lrow][c + 5] = bf2f((u16)(uv.z >> 16));
            Vl[lrow][c + 6] = bf2f((u16)(uv.w & 0xffffu)); Vl[lrow][c + 7] = bf2f((u16)(uv.w >> 16));
        }
        __syncthreads();

        const int krel = qi - kt * 64;  // keys ki <= krel are valid
        for (int ki = 0; ki < 64; ++ki) {
            if (ki <= krel) {
                // dot(q, K[ki]) with 4 partial chains to break FMA latency
                float s0 = 0.f, s1 = 0.f, s2 = 0.f, s3 = 0.f;
#pragma unroll
                for (int dd = 0; dd < 64; dd += 4) {
                    s0 = fmaf(q[dd + 0], Kl[ki][dd + 0], s0);
                    s1 = fmaf(q[dd + 1], Kl[ki][dd + 1], s1);
                    s2 = fmaf(q[dd + 2], Kl[ki][dd + 2], s2);
                    s3 = fmaf(q[dd + 3], Kl[ki][dd + 3], s3);
                }
                float s = (s0 + s1) + (s2 + s3);
                if (s > mrun) {
                    float corr = __expf(mrun - s);
                    lrun *= corr;
#pragma unroll
                    for (int dd = 0; dd < 64; ++dd) acc[dd] *= corr;
                    mrun = s;
                }
                float p = __expf(s - mrun);
                lrun += p;
#pragma unroll
                for (int dd = 0; dd < 64; ++dd) acc[dd] = fmaf(p, Vl[ki][dd], acc[dd]);
            }
        }
        __syncthreads();
    }

    const float inv = 1.f / lrun;
    u16* yp = y + ((size_t)(b * Tt + qi) * Cc + h * 64);
#pragma unroll
    for (int s = 0; s < 8; ++s) {
        ushort4 p0, p1;
        p0.x = f2bf(acc[s * 8 + 0] * inv); p0.y = f2bf(acc[s * 8 + 1] * inv);
        p0.z = f2bf(acc[s * 8 + 2] * inv); p0.w = f2bf(acc[s * 8 + 3] * inv);
        p1.x = f2bf(acc[s * 8 + 4] * inv); p1.y = f2bf(acc[s * 8 + 5] * inv);
        p1.z = f2bf(acc[s * 8 + 6] * inv); p1.w = f2bf(acc[s * 8 + 7] * inv);
        *reinterpret_cast<ushort4*>(yp + s * 8 + 0) = p0;
        *reinterpret_cast<ushort4*>(yp + s * 8 + 4) = p1;
    }
}

extern "C" void kernel_launch(void* const* d_in, const int* in_sizes, int n_in,
                              void* d_out, int out_size, void* d_ws, size_t ws_size,
                              hipStream_t stream) {
    const float* x    = (const float*)d_in[0];
    const float* Wqkv = (const float*)d_in[1];
    const float* Wout = (const float*)d_in[2];
    float* out = (float*)d_out;

    // ws layout: qkv bf16 [8192 x 3072] (50.3 MB) | y bf16 [8192 x 1024] (16.8 MB)
    u16* qkv = (u16*)d_ws;
    u16* y   = qkv + (size_t)Mm * C3;

    dim3 g1(Mm / 64, C3 / 64);
    gemm_xqkv<<<g1, 256, 0, stream>>>(x, Wqkv, qkv, C3, Cc);

    attn_flash<<<Bb * Hh * (Tt / 256), 256, 0, stream>>>(qkv, y);

    dim3 g2(Mm / 64, Cc / 64);
    gemm_yout<<<g2, 256, 0, stream>>>(y, Wout, out, Cc, Cc);
}

// Round 2
// 444.878 us; speedup vs baseline: 5.0243x; 5.0243x over previous
//
#include <hip/hip_runtime.h>
#include <hip/hip_bf16.h>

typedef unsigned short u16;
typedef __attribute__((ext_vector_type(8))) short short8v;   // 8 bf16 = 4 VGPR
typedef __attribute__((ext_vector_type(4))) float f32x4;     // mfma 16x16 acc

#define Bb 4
#define Tt 2048
#define Cc 1024
#define Hh 16
#define C3 3072
#define Mm 8192

__device__ __forceinline__ float bf2f(u16 u) {
    return __uint_as_float(((unsigned int)u) << 16);
}
__device__ __forceinline__ u16 f2bf(float f) {
    unsigned int x = __float_as_uint(f);
    return (u16)((x + 0x7fffu + ((x >> 16) & 1u)) >> 16);
}
__device__ __forceinline__ unsigned int pk2(float a, float b) {
    return (unsigned int)f2bf(a) | ((unsigned int)f2bf(b) << 16);
}

// ---------- convert x f32 -> bf16 ----------
__global__ __launch_bounds__(256) void cvt_x(const float* __restrict__ in,
                                             u16* __restrict__ out) {
    int i = blockIdx.x * 256 + threadIdx.x;
    float4 v = reinterpret_cast<const float4*>(in)[i];
    ushort4 o;
    o.x = f2bf(v.x); o.y = f2bf(v.y); o.z = f2bf(v.z); o.w = f2bf(v.w);
    reinterpret_cast<ushort4*>(out)[i] = o;
}

// ---------- transpose+convert W [R][Ccols] f32 -> W^T [Ccols][R] bf16 ----------
__global__ __launch_bounds__(256) void wtrans(const float* __restrict__ in,
                                              u16* __restrict__ out,
                                              int R, int Ccols) {
    __shared__ float t[32][33];
    const int tx = threadIdx.x & 31, ty = threadIdx.x >> 5;  // 32x8
    const int bx = blockIdx.x, by = blockIdx.y;
    const int c = bx * 32 + tx;
#pragma unroll
    for (int j = 0; j < 4; ++j) {
        int r = by * 32 + ty + j * 8;
        t[ty + j * 8][tx] = in[(size_t)r * Ccols + c];
    }
    __syncthreads();
#pragma unroll
    for (int j = 0; j < 4; ++j) {
        int orow = bx * 32 + ty + j * 8;   // original col
        int oc   = by * 32 + tx;           // original row
        out[(size_t)orow * R + oc] = f2bf(t[tx][ty + j * 8]);
    }
}

// ---------- bf16 MFMA GEMM: C[M][N] = A[M][K] * BT[N][K]^T ----------
// 128x128 tile, 4 waves (2x2 of 64x64), 16x16x32 mfma, BK=32, padded LDS rows.
template <int OUTF32>
__global__ __launch_bounds__(256) void gemm_mfma(const u16* __restrict__ A,
                                                 const u16* __restrict__ BT,
                                                 void* __restrict__ Cout,
                                                 int M, int N, int K) {
    __shared__ u16 As[128 * 40];
    __shared__ u16 Bs[128 * 40];
    const int tid = threadIdx.x;
    const int w = tid >> 6, l = tid & 63;
    const int wr = w >> 1, wc = w & 1;
    const int g = l >> 4, q = l & 15;
    const int bm = blockIdx.x * 128, bn = blockIdx.y * 128;
    const int lrow = tid >> 2, lk = (tid & 3) * 8;

    f32x4 acc[4][4] = {};
    const u16* Ap = A + (size_t)(bm + lrow) * K + lk;
    const u16* Bp = BT + (size_t)(bn + lrow) * K + lk;

    for (int k0 = 0; k0 < K; k0 += 32) {
        uint4 a0 = *reinterpret_cast<const uint4*>(Ap + k0);
        uint4 a1 = *reinterpret_cast<const uint4*>(Ap + (size_t)64 * K + k0);
        uint4 b0 = *reinterpret_cast<const uint4*>(Bp + k0);
        uint4 b1 = *reinterpret_cast<const uint4*>(Bp + (size_t)64 * K + k0);
        __syncthreads();  // prior-iteration fragment reads complete
        *reinterpret_cast<uint4*>(&As[lrow * 40 + lk]) = a0;
        *reinterpret_cast<uint4*>(&As[(64 + lrow) * 40 + lk]) = a1;
        *reinterpret_cast<uint4*>(&Bs[lrow * 40 + lk]) = b0;
        *reinterpret_cast<uint4*>(&Bs[(64 + lrow) * 40 + lk]) = b1;
        __syncthreads();
        short8v af[4], bf[4];
#pragma unroll
        for (int m = 0; m < 4; ++m)
            af[m] = *reinterpret_cast<const short8v*>(&As[(wr * 64 + m * 16 + q) * 40 + g * 8]);
#pragma unroll
        for (int n = 0; n < 4; ++n)
            bf[n] = *reinterpret_cast<const short8v*>(&Bs[(wc * 64 + n * 16 + q) * 40 + g * 8]);
#pragma unroll
        for (int m = 0; m < 4; ++m)
#pragma unroll
            for (int n = 0; n < 4; ++n)
                acc[m][n] = __builtin_amdgcn_mfma_f32_16x16x32_bf16(af[m], bf[n], acc[m][n], 0, 0, 0);
    }

#pragma unroll
    for (int m = 0; m < 4; ++m)
#pragma unroll
        for (int n = 0; n < 4; ++n)
#pragma unroll
            for (int r = 0; r < 4; ++r) {
                int row = bm + wr * 64 + m * 16 + g * 4 + r;
                int col = bn + wc * 64 + n * 16 + q;
                if (OUTF32)
                    reinterpret_cast<float*>(Cout)[(size_t)row * N + col] = acc[m][n][r];
                else
                    reinterpret_cast<u16*>(Cout)[(size_t)row * N + col] = f2bf(acc[m][n][r]);
            }
}

// ---------- MFMA flash attention (causal) ----------
// Block: 256 thr = 4 waves, one (b,h), 64 queries (16/wave). Key steps of 32.
// S^T = mfma(A=K, B=Q)  -> lane holds S^T[key=4g+r (+16t)][q=l&15]
// O^T accumulated as 4 d-tiles: lane holds O^T[d=dt*16+4g+r][q=l&15]
__global__ __launch_bounds__(256) void attn_mfma(const u16* __restrict__ qkv,
                                                 u16* __restrict__ y) {
    __shared__ u16 Vt[2][64 * 40];   // V^T tile: [d=64][key=32 (+pad to 40)]
    __shared__ u16 Pl[4][16 * 40];   // per-wave P: [q=16][key=32 (+pad)]
    const int tid = threadIdx.x;
    const int w = tid >> 6, l = tid & 63;
    const int g = l >> 4, q16 = l & 15;
    const int bid = blockIdx.x;
    const int qb = bid & 31, h = (bid >> 5) & 15, b = bid >> 9;
    const int qw0 = qb * 64 + w * 16;
    const int qg = qw0 + q16;
    const int tokq = b * Tt + qg;

    // Q fragments (also used as mfma B operand): lane holds Q[q=l&15][d=(l>>4)*8+j]
    const u16* qp = qkv + (size_t)tokq * C3 + h * 64;
    short8v qf0 = *reinterpret_cast<const short8v*>(qp + g * 8);
    short8v qf1 = *reinterpret_cast<const short8v*>(qp + 32 + g * 8);

    f32x4 accO[4] = {};
    float m_run = -1e30f, l_run = 0.f;

    const int nsteps = 2 * qb + 2;
    const int vkey = tid >> 3, vds = (tid & 7) * 8;  // V stage: 32 keys x 64 d

    for (int kt = 0; kt < nsteps; ++kt) {
        // ---- stage V^T tile (double-buffered, one barrier/step) ----
        const u16* vp = qkv + (size_t)(b * Tt + kt * 32 + vkey) * C3 + 2048 + h * 64 + vds;
        uint4 vv = *reinterpret_cast<const uint4*>(vp);
        u16* vb = &Vt[kt & 1][0];
        vb[(vds + 0) * 40 + vkey] = (u16)(vv.x & 0xffffu);
        vb[(vds + 1) * 40 + vkey] = (u16)(vv.x >> 16);
        vb[(vds + 2) * 40 + vkey] = (u16)(vv.y & 0xffffu);
        vb[(vds + 3) * 40 + vkey] = (u16)(vv.y >> 16);
        vb[(vds + 4) * 40 + vkey] = (u16)(vv.z & 0xffffu);
        vb[(vds + 5) * 40 + vkey] = (u16)(vv.z >> 16);
        vb[(vds + 6) * 40 + vkey] = (u16)(vv.w & 0xffffu);
        vb[(vds + 7) * 40 + vkey] = (u16)(vv.w >> 16);
        __syncthreads();

        if (kt * 32 <= qw0 + 15) {  // wave has at least one valid (q,key) pair
            // ---- S^T = K * Q^T via mfma ----
            f32x4 st[2] = {};
            const u16* kpb = qkv + (size_t)(b * Tt + kt * 32) * C3 + 1024 + h * 64;
#pragma unroll
            for (int t = 0; t < 2; ++t) {
                const u16* kp = kpb + (size_t)(t * 16 + q16) * C3;
                short8v kf0 = *reinterpret_cast<const short8v*>(kp + g * 8);
                short8v kf1 = *reinterpret_cast<const short8v*>(kp + 32 + g * 8);
                st[t] = __builtin_amdgcn_mfma_f32_16x16x32_bf16(kf0, qf0, st[t], 0, 0, 0);
                st[t] = __builtin_amdgcn_mfma_f32_16x16x32_bf16(kf1, qf1, st[t], 0, 0, 0);
            }
            // ---- scale + causal mask ----
            const bool needmask = (kt * 32 + 31 > qw0);
            float s[2][4];
#pragma unroll
            for (int t = 0; t < 2; ++t)
#pragma unroll
                for (int r = 0; r < 4; ++r) {
                    float v = st[t][r] * 0.125f;
                    int keyg = kt * 32 + t * 16 + 4 * g + r;
                    if (needmask && keyg > qg) v = -1e30f;
                    s[t][r] = v;
                }
            // ---- online softmax (row = q, lane-local; reduce over groups) ----
            float lm = s[0][0];
#pragma unroll
            for (int t = 0; t < 2; ++t)
#pragma unroll
                for (int r = 0; r < 4; ++r) lm = fmaxf(lm, s[t][r]);
            lm = fmaxf(lm, __shfl_xor(lm, 16));
            lm = fmaxf(lm, __shfl_xor(lm, 32));
            float m_new = fmaxf(m_run, lm);
            float alpha = __expf(m_run - m_new);
            float p[2][4];
            float rs = 0.f;
#pragma unroll
            for (int t = 0; t < 2; ++t)
#pragma unroll
                for (int r = 0; r < 4; ++r) {
                    p[t][r] = __expf(s[t][r] - m_new);
                    rs += p[t][r];
                }
            rs += __shfl_xor(rs, 16);
            rs += __shfl_xor(rs, 32);
            l_run = l_run * alpha + rs;
            m_run = m_new;
#pragma unroll
            for (int dt = 0; dt < 4; ++dt) accO[dt] *= alpha;

            // ---- P -> bf16 via wave-private LDS (layout [q][key]) ----
            unsigned int* pw = reinterpret_cast<unsigned int*>(&Pl[w][0]);
#pragma unroll
            for (int t = 0; t < 2; ++t) {
                int base = q16 * 20 + 8 * t + 2 * g;
                pw[base + 0] = pk2(p[t][0], p[t][1]);
                pw[base + 1] = pk2(p[t][2], p[t][3]);
            }
            asm volatile("" ::: "memory");
            short8v pf = *reinterpret_cast<const short8v*>(&Pl[w][q16 * 40 + 8 * g]);

            // ---- O^T += V^T * P^T ----
            const u16* vbr = &Vt[kt & 1][0];
#pragma unroll
            for (int dt = 0; dt < 4; ++dt) {
                short8v vf = *reinterpret_cast<const short8v*>(&vbr[(dt * 16 + q16) * 40 + g * 8]);
                accO[dt] = __builtin_amdgcn_mfma_f32_16x16x32_bf16(vf, pf, accO[dt], 0, 0, 0);
            }
        }
    }

    // ---- normalize + store: y[tok(q)][h*64 + d] ----
    const float inv = 1.f / l_run;
    u16* yp = y + (size_t)tokq * Cc + h * 64;
#pragma unroll
    for (int dt = 0; dt < 4; ++dt)
#pragma unroll
        for (int r = 0; r < 4; ++r) {
            int d = dt * 16 + 4 * g + r;
            yp[d] = f2bf(accO[dt][r] * inv);
        }
}

extern "C" void kernel_launch(void* const* d_in, const int* in_sizes, int n_in,
                              void* d_out, int out_size, void* d_ws, size_t ws_size,
                              hipStream_t stream) {
    const float* x    = (const float*)d_in[0];
    const float* Wqkv = (const float*)d_in[1];
    const float* Wout = (const float*)d_in[2];
    float* out = (float*)d_out;

    // ws layout (bytes):
    //   qkv bf16 [8192][3072]             @ 0        (50,331,648)
    //   x_bf bf16 [8192][1024] (later y)  @ 50331648 (16,777,216)
    //   WqkvT bf16 [3072][1024]           @ 67108864 ( 6,291,456)
    //   WoutT bf16 [1024][1024]           @ 73400320 ( 2,097,152)
    char* ws = (char*)d_ws;
    u16* qkv   = (u16*)(ws);
    u16* xbf   = (u16*)(ws + 50331648);  // aliased as y after GEMM1
    u16* WqkvT = (u16*)(ws + 67108864);
    u16* WoutT = (u16*)(ws + 73400320);

    cvt_x<<<(Mm * Cc) / (256 * 4), 256, 0, stream>>>(x, xbf);
    wtrans<<<dim3(C3 / 32, Cc / 32), 256, 0, stream>>>(Wqkv, WqkvT, Cc, C3);
    wtrans<<<dim3(Cc / 32, Cc / 32), 256, 0, stream>>>(Wout, WoutT, Cc, Cc);

    gemm_mfma<0><<<dim3(Mm / 128, C3 / 128), 256, 0, stream>>>(xbf, WqkvT, qkv, Mm, C3, Cc);

    u16* ybf = xbf;  // x_bf dead after GEMM1; reuse region for y
    attn_mfma<<<Bb * Hh * (Tt / 64), 256, 0, stream>>>(qkv, ybf);

    gemm_mfma<1><<<dim3(Mm / 128, Cc / 128), 256, 0, stream>>>(ybf, WoutT, out, Mm, Cc, Cc);
}

// Round 3
// 234.465 us; speedup vs baseline: 9.5332x; 1.8974x over previous
//
#include <hip/hip_runtime.h>
#include <hip/hip_bf16.h>

typedef unsigned short u16;
typedef __attribute__((ext_vector_type(8))) short short8v;   // 8 bf16 = 4 VGPR
typedef __attribute__((ext_vector_type(4))) float f32x4;     // mfma 16x16 acc
typedef __attribute__((ext_vector_type(16))) float f32x16;   // mfma 32x32 acc

#define Bb 4
#define Tt 2048
#define Cc 1024
#define Hh 16
#define C3 3072
#define Mm 8192

__device__ __forceinline__ float bf2f(u16 u) {
    return __uint_as_float(((unsigned int)u) << 16);
}
__device__ __forceinline__ u16 f2bf(float f) {
    unsigned int x = __float_as_uint(f);
    return (u16)((x + 0x7fffu + ((x >> 16) & 1u)) >> 16);
}
__device__ __forceinline__ unsigned int pk2(float a, float b) {
    return (unsigned int)f2bf(a) | ((unsigned int)f2bf(b) << 16);
}

__device__ __forceinline__ void plswap(unsigned int& a, unsigned int& b) {
#if __has_builtin(__builtin_amdgcn_permlane32_swap)
    typedef __attribute__((ext_vector_type(2))) unsigned int uint2v;
    uint2v r = __builtin_amdgcn_permlane32_swap(a, b, false, false);
    a = r.x; b = r.y;
#else
    asm volatile("v_permlane32_swap_b32 %0, %1" : "+v"(a), "+v"(b));
#endif
}

// ---------- convert x f32 -> bf16 ----------
__global__ __launch_bounds__(256) void cvt_x(const float* __restrict__ in,
                                             u16* __restrict__ out) {
    int i = blockIdx.x * 256 + threadIdx.x;
    float4 v = reinterpret_cast<const float4*>(in)[i];
    ushort4 o;
    o.x = f2bf(v.x); o.y = f2bf(v.y); o.z = f2bf(v.z); o.w = f2bf(v.w);
    reinterpret_cast<ushort4*>(out)[i] = o;
}

// ---------- transpose+convert W [R][Ccols] f32 -> W^T [Ccols][R] bf16 ----------
__global__ __launch_bounds__(256) void wtrans(const float* __restrict__ in,
                                              u16* __restrict__ out,
                                              int R, int Ccols) {
    __shared__ float t[32][33];
    const int tx = threadIdx.x & 31, ty = threadIdx.x >> 5;  // 32x8
    const int bx = blockIdx.x, by = blockIdx.y;
    const int c = bx * 32 + tx;
#pragma unroll
    for (int j = 0; j < 4; ++j) {
        int r = by * 32 + ty + j * 8;
        t[ty + j * 8][tx] = in[(size_t)r * Ccols + c];
    }
    __syncthreads();
#pragma unroll
    for (int j = 0; j < 4; ++j) {
        int orow = bx * 32 + ty + j * 8;
        int oc   = by * 32 + tx;
        out[(size_t)orow * R + oc] = f2bf(t[tx][ty + j * 8]);
    }
}

// ---------- bf16 MFMA GEMM: C[M][N] = A[M][K] * BT[N][K]^T (unchanged) ----------
template <int OUTF32>
__global__ __launch_bounds__(256) void gemm_mfma(const u16* __restrict__ A,
                                                 const u16* __restrict__ BT,
                                                 void* __restrict__ Cout,
                                                 int M, int N, int K) {
    __shared__ u16 As[128 * 40];
    __shared__ u16 Bs[128 * 40];
    const int tid = threadIdx.x;
    const int w = tid >> 6, l = tid & 63;
    const int wr = w >> 1, wc = w & 1;
    const int g = l >> 4, q = l & 15;
    const int bm = blockIdx.x * 128, bn = blockIdx.y * 128;
    const int lrow = tid >> 2, lk = (tid & 3) * 8;

    f32x4 acc[4][4] = {};
    const u16* Ap = A + (size_t)(bm + lrow) * K + lk;
    const u16* Bp = BT + (size_t)(bn + lrow) * K + lk;

    for (int k0 = 0; k0 < K; k0 += 32) {
        uint4 a0 = *reinterpret_cast<const uint4*>(Ap + k0);
        uint4 a1 = *reinterpret_cast<const uint4*>(Ap + (size_t)64 * K + k0);
        uint4 b0 = *reinterpret_cast<const uint4*>(Bp + k0);
        uint4 b1 = *reinterpret_cast<const uint4*>(Bp + (size_t)64 * K + k0);
        __syncthreads();
        *reinterpret_cast<uint4*>(&As[lrow * 40 + lk]) = a0;
        *reinterpret_cast<uint4*>(&As[(64 + lrow) * 40 + lk]) = a1;
        *reinterpret_cast<uint4*>(&Bs[lrow * 40 + lk]) = b0;
        *reinterpret_cast<uint4*>(&Bs[(64 + lrow) * 40 + lk]) = b1;
        __syncthreads();
        short8v af[4], bf[4];
#pragma unroll
        for (int m = 0; m < 4; ++m)
            af[m] = *reinterpret_cast<const short8v*>(&As[(wr * 64 + m * 16 + q) * 40 + g * 8]);
#pragma unroll
        for (int n = 0; n < 4; ++n)
            bf[n] = *reinterpret_cast<const short8v*>(&Bs[(wc * 64 + n * 16 + q) * 40 + g * 8]);
#pragma unroll
        for (int m = 0; m < 4; ++m)
#pragma unroll
            for (int n = 0; n < 4; ++n)
                acc[m][n] = __builtin_amdgcn_mfma_f32_16x16x32_bf16(af[m], bf[n], acc[m][n], 0, 0, 0);
    }

#pragma unroll
    for (int m = 0; m < 4; ++m)
#pragma unroll
        for (int n = 0; n < 4; ++n)
#pragma unroll
            for (int r = 0; r < 4; ++r) {
                int row = bm + wr * 64 + m * 16 + g * 4 + r;
                int col = bn + wc * 64 + n * 16 + q;
                if (OUTF32)
                    reinterpret_cast<float*>(Cout)[(size_t)row * N + col] = acc[m][n][r];
                else
                    reinterpret_cast<u16*>(Cout)[(size_t)row * N + col] = f2bf(acc[m][n][r]);
            }
}

// ---------- MFMA flash attention (causal), 32x32 structure ----------
// 4 waves x 32 q = 128 q per chunk; block does chunk pair (c, 15-c): uniform work.
// KV step = 64 keys. K LDS [64][72] row-major; V^T LDS [64][72] (d-major).
// S^T = mfma(A=K, B=Q): lane holds S^T[key][q=l&31]; softmax lane-local + shfl(32).
// P repack: pk2 + permlane32_swap -> B-frags. O^T = mfma(A=V^T, B=P).
__global__ __launch_bounds__(256) void attn_mfma(const u16* __restrict__ qkv,
                                                 u16* __restrict__ y) {
    __shared__ u16 SM[18432];   // 36,864 B: K dbuf 2x4608 | V^T dbuf 2x4608
    const int tid = threadIdx.x;
    const int w = tid >> 6, l = tid & 63;
    const int q31 = l & 31, hi = l >> 5;
    const int bid = blockIdx.x;
    const int bh = bid >> 3, c0 = bid & 7;
    const int b = bh >> 4, h = bh & 15;
    const size_t tok0 = (size_t)b * Tt;

    // staging ids: 256 thr cover 64 keys x 8 d-segs (2 segs each)
    const int skey = tid >> 2;
    const int sseg = (tid & 3) * 2;
    const int kp = skey >> 1;          // V^T dword column
    const int veo = (skey & 1) * 4;    // e-range split by key parity

    for (int phase = 0; phase < 2; ++phase) {
        const int chunk = phase ? (15 - c0) : c0;
        const int nsteps = 2 * (chunk + 1);
        const int q0w = chunk * 128 + w * 32;
        const int qlane = q0w + q31;

        // Q fragments: B-operand, lane holds Q[q=l&31][d = 16s + 8hi + j]
        short8v qf0, qf1, qf2, qf3;
        {
            const u16* qp = qkv + (tok0 + qlane) * C3 + h * 64 + hi * 8;
            qf0 = *reinterpret_cast<const short8v*>(qp);
            qf1 = *reinterpret_cast<const short8v*>(qp + 16);
            qf2 = *reinterpret_cast<const short8v*>(qp + 32);
            qf3 = *reinterpret_cast<const short8v*>(qp + 48);
        }

        f32x16 acc0 = {}, acc1 = {};
        float m_run = -1e30f, l_run = 0.f;

        // ---- prologue: stage step 0 into buf 0 ----
        {
            const u16* gp = qkv + (tok0 + skey) * C3 + 1024 + h * 64 + sseg * 8;
            uint4 ka = *reinterpret_cast<const uint4*>(gp);
            uint4 kb = *reinterpret_cast<const uint4*>(gp + 8);
            uint4 va = *reinterpret_cast<const uint4*>(gp + 1024);
            uint4 vb = *reinterpret_cast<const uint4*>(gp + 1032);
            u16* Kd = SM;
            *reinterpret_cast<uint4*>(&Kd[skey * 72 + sseg * 8]) = ka;
            *reinterpret_cast<uint4*>(&Kd[skey * 72 + sseg * 8 + 8]) = kb;
            uint4 pa, pb;
            pa.x = __shfl_xor(va.x, 4); pa.y = __shfl_xor(va.y, 4);
            pa.z = __shfl_xor(va.z, 4); pa.w = __shfl_xor(va.w, 4);
            pb.x = __shfl_xor(vb.x, 4); pb.y = __shfl_xor(vb.y, 4);
            pb.z = __shfl_xor(vb.z, 4); pb.w = __shfl_xor(vb.w, 4);
            union UU { uint4 v; u16 hh[8]; };
            UU o0, o1, p0u, p1u;
            o0.v = va; o1.v = vb; p0u.v = pa; p1u.v = pb;
            unsigned int* Od = reinterpret_cast<unsigned int*>(SM + 9216);
#pragma unroll
            for (int i = 0; i < 4; ++i) {
                int e = veo + i;
                unsigned int w0 = (skey & 1)
                    ? ((unsigned)p0u.hh[e] | ((unsigned)o0.hh[e] << 16))
                    : ((unsigned)o0.hh[e] | ((unsigned)p0u.hh[e] << 16));
                unsigned int w1 = (skey & 1)
                    ? ((unsigned)p1u.hh[e] | ((unsigned)o1.hh[e] << 16))
                    : ((unsigned)o1.hh[e] | ((unsigned)p1u.hh[e] << 16));
                Od[(sseg * 8 + e) * 36 + kp] = w0;
                Od[(sseg * 8 + 8 + e) * 36 + kp] = w1;
            }
        }
        __syncthreads();

        for (int t = 0; t < nsteps; ++t) {
            const int cur = t & 1;
            const int k0 = t * 64;
            const bool pre = (t + 1 < nsteps);
            uint4 ka = {}, kb = {}, va = {}, vb = {};
            if (pre) {
                const u16* gp = qkv + (tok0 + (t + 1) * 64 + skey) * C3 + 1024 + h * 64 + sseg * 8;
                ka = *reinterpret_cast<const uint4*>(gp);
                kb = *reinterpret_cast<const uint4*>(gp + 8);
                va = *reinterpret_cast<const uint4*>(gp + 1024);
                vb = *reinterpret_cast<const uint4*>(gp + 1032);
            }

            if (k0 <= q0w + 31) {   // wave-uniform validity
                const u16* Kb = SM + cur * 4608;
                const u16* Vb = SM + 9216 + cur * 4608;
                // ---- S^T = K Q^T ----
                f32x16 st0 = {}, st1 = {};
#pragma unroll
                for (int s = 0; s < 4; ++s) {
                    short8v kfa = *reinterpret_cast<const short8v*>(&Kb[q31 * 72 + s * 16 + hi * 8]);
                    short8v kfb = *reinterpret_cast<const short8v*>(&Kb[(q31 + 32) * 72 + s * 16 + hi * 8]);
                    short8v qs = (s == 0) ? qf0 : (s == 1) ? qf1 : (s == 2) ? qf2 : qf3;
                    st0 = __builtin_amdgcn_mfma_f32_32x32x16_bf16(kfa, qs, st0, 0, 0, 0);
                    st1 = __builtin_amdgcn_mfma_f32_32x32x16_bf16(kfb, qs, st1, 0, 0, 0);
                }
                // ---- scale + causal mask + max ----
                const bool diag = (k0 + 63 > q0w);
                float p0[16], p1[16];
                float mx = -1e30f;
#pragma unroll
                for (int r = 0; r < 16; ++r) {
                    int krel = (r & 3) + 8 * (r >> 2) + 4 * hi;
                    float v0 = st0[r] * 0.125f;
                    float v1 = st1[r] * 0.125f;
                    if (diag) {
                        if (k0 + krel > qlane) v0 = -1e30f;
                        if (k0 + 32 + krel > qlane) v1 = -1e30f;
                    }
                    p0[r] = v0; p1[r] = v1;
                    mx = fmaxf(mx, fmaxf(v0, v1));
                }
                mx = fmaxf(mx, __shfl_xor(mx, 32));
                float m_new = fmaxf(m_run, mx);
                float alpha = __expf(m_run - m_new);
                float rs = 0.f;
#pragma unroll
                for (int r = 0; r < 16; ++r) {
                    p0[r] = __expf(p0[r] - m_new);
                    p1[r] = __expf(p1[r] - m_new);
                    rs += p0[r] + p1[r];
                }
                rs += __shfl_xor(rs, 32);
                l_run = l_run * alpha + rs;
                m_run = m_new;
                acc0 *= alpha;
                acc1 *= alpha;

                // ---- P -> bf16 B-frags via pk2 + permlane32_swap ----
                short8v pf0, pf1, pf2, pf3;
#define MKFRAG(dst, P, rb)                                                  \
                {                                                           \
                    unsigned int a_ = pk2(P[rb + 0], P[rb + 1]);            \
                    unsigned int b_ = pk2(P[rb + 4], P[rb + 5]);            \
                    unsigned int c_ = pk2(P[rb + 2], P[rb + 3]);            \
                    unsigned int d_ = pk2(P[rb + 6], P[rb + 7]);            \
                    plswap(a_, b_);                                         \
                    plswap(c_, d_);                                         \
                    union { unsigned int u[4]; short8v s; } uf_;            \
                    uf_.u[0] = a_; uf_.u[1] = c_; uf_.u[2] = b_; uf_.u[3] = d_; \
                    dst = uf_.s;                                            \
                }
                MKFRAG(pf0, p0, 0)
                MKFRAG(pf1, p0, 8)
                MKFRAG(pf2, p1, 0)
                MKFRAG(pf3, p1, 8)
#undef MKFRAG
                // ---- O^T += V^T P^T ----
#pragma unroll
                for (int s = 0; s < 4; ++s) {
                    short8v vfa = *reinterpret_cast<const short8v*>(&Vb[q31 * 72 + s * 16 + hi * 8]);
                    short8v vfb = *reinterpret_cast<const short8v*>(&Vb[(q31 + 32) * 72 + s * 16 + hi * 8]);
                    short8v ps = (s == 0) ? pf0 : (s == 1) ? pf1 : (s == 2) ? pf2 : pf3;
                    acc0 = __builtin_amdgcn_mfma_f32_32x32x16_bf16(vfa, ps, acc0, 0, 0, 0);
                    acc1 = __builtin_amdgcn_mfma_f32_32x32x16_bf16(vfb, ps, acc1, 0, 0, 0);
                }
            }

            if (pre) {
                u16* Kd = SM + (cur ^ 1) * 4608;
                *reinterpret_cast<uint4*>(&Kd[skey * 72 + sseg * 8]) = ka;
                *reinterpret_cast<uint4*>(&Kd[skey * 72 + sseg * 8 + 8]) = kb;
                uint4 pa, pb;
                pa.x = __shfl_xor(va.x, 4); pa.y = __shfl_xor(va.y, 4);
                pa.z = __shfl_xor(va.z, 4); pa.w = __shfl_xor(va.w, 4);
                pb.x = __shfl_xor(vb.x, 4); pb.y = __shfl_xor(vb.y, 4);
                pb.z = __shfl_xor(vb.z, 4); pb.w = __shfl_xor(vb.w, 4);
                union UU { uint4 v; u16 hh[8]; };
                UU o0, o1, p0u, p1u;
                o0.v = va; o1.v = vb; p0u.v = pa; p1u.v = pb;
                unsigned int* Od = reinterpret_cast<unsigned int*>(SM + 9216 + (cur ^ 1) * 4608);
#pragma unroll
                for (int i = 0; i < 4; ++i) {
                    int e = veo + i;
                    unsigned int w0 = (skey & 1)
                        ? ((unsigned)p0u.hh[e] | ((unsigned)o0.hh[e] << 16))
                        : ((unsigned)o0.hh[e] | ((unsigned)p0u.hh[e] << 16));
                    unsigned int w1 = (skey & 1)
                        ? ((unsigned)p1u.hh[e] | ((unsigned)o1.hh[e] << 16))
                        : ((unsigned)o1.hh[e] | ((unsigned)p1u.hh[e] << 16));
                    Od[(sseg * 8 + e) * 36 + kp] = w0;
                    Od[(sseg * 8 + 8 + e) * 36 + kp] = w1;
                }
            }
            __syncthreads();
        }

        // ---- store O: LDS transpose -> coalesced 16B stores ----
        const float inv = 1.f / l_run;
        unsigned int* Od2 = reinterpret_cast<unsigned int*>(SM);
        const int qrow = w * 32 + q31;
#pragma unroll
        for (int r = 0; r < 16; r += 2) {
            int d0 = (r & 3) + 8 * (r >> 2) + 4 * hi;   // even
            Od2[qrow * 36 + (d0 >> 1)] = pk2(acc0[r] * inv, acc0[r + 1] * inv);
            Od2[qrow * 36 + ((32 + d0) >> 1)] = pk2(acc1[r] * inv, acc1[r + 1] * inv);
        }
        __syncthreads();
        {
            const int row = w * 32 + (l >> 1);
            const int dh = (l & 1) * 32;
            const u16* src = SM + row * 72 + dh;
            u16* dst = y + (tok0 + chunk * 128 + row) * Cc + h * 64 + dh;
#pragma unroll
            for (int k2 = 0; k2 < 4; ++k2)
                *reinterpret_cast<uint4*>(dst + k2 * 8) =
                    *reinterpret_cast<const uint4*>(src + k2 * 8);
        }
        __syncthreads();   // protect SM before next phase's staging
    }
}

extern "C" void kernel_launch(void* const* d_in, const int* in_sizes, int n_in,
                              void* d_out, int out_size, void* d_ws, size_t ws_size,
                              hipStream_t stream) {
    const float* x    = (const float*)d_in[0];
    const float* Wqkv = (const float*)d_in[1];
    const float* Wout = (const float*)d_in[2];
    float* out = (float*)d_out;

    char* ws = (char*)d_ws;
    u16* qkv   = (u16*)(ws);
    u16* xbf   = (u16*)(ws + 50331648);  // aliased as y after GEMM1
    u16* WqkvT = (u16*)(ws + 67108864);
    u16* WoutT = (u16*)(ws + 73400320);

    cvt_x<<<(Mm * Cc) / (256 * 4), 256, 0, stream>>>(x, xbf);
    wtrans<<<dim3(C3 / 32, Cc / 32), 256, 0, stream>>>(Wqkv, WqkvT, Cc, C3);
    wtrans<<<dim3(Cc / 32, Cc / 32), 256, 0, stream>>>(Wout, WoutT, Cc, Cc);

    gemm_mfma<0><<<dim3(Mm / 128, C3 / 128), 256, 0, stream>>>(xbf, WqkvT, qkv, Mm, C3, Cc);

    u16* ybf = xbf;
    attn_mfma<<<512, 256, 0, stream>>>(qkv, ybf);

    gemm_mfma<1><<<dim3(Mm / 128, Cc / 128), 256, 0, stream>>>(ybf, WoutT, out, Mm, Cc, Cc);
}

// Round 4
// 220.701 us; speedup vs baseline: 10.1277x; 1.0624x over previous
//
#include <hip/hip_runtime.h>
#include <hip/hip_bf16.h>

typedef unsigned short u16;
typedef __attribute__((ext_vector_type(8))) short short8v;   // 8 bf16 = 4 VGPR
typedef __attribute__((ext_vector_type(4))) float f32x4;     // mfma 16x16 acc
typedef __attribute__((ext_vector_type(16))) float f32x16;   // mfma 32x32 acc

#define Bb 4
#define Tt 2048
#define Cc 1024
#define Hh 16
#define C3 3072
#define Mm 8192

__device__ __forceinline__ u16 f2bf(float f) {
    union { __hip_bfloat16 h; u16 u; } r;
    r.h = __float2bfloat16(f);
    return r.u;
}
__device__ __forceinline__ unsigned int pk2(float a, float b) {
    union { __hip_bfloat162 h; unsigned int u; } r;
    r.h.x = __float2bfloat16(a);
    r.h.y = __float2bfloat16(b);
    return r.u;
}
__device__ __forceinline__ float exp2g(float x) {
#if __has_builtin(__builtin_amdgcn_exp2f)
    return __builtin_amdgcn_exp2f(x);
#else
    return exp2f(x);
#endif
}
__device__ __forceinline__ void plswap(unsigned int& a, unsigned int& b) {
#if __has_builtin(__builtin_amdgcn_permlane32_swap)
    typedef __attribute__((ext_vector_type(2))) unsigned int uint2v;
    uint2v r = __builtin_amdgcn_permlane32_swap(a, b, false, false);
    a = r.x; b = r.y;
#else
    asm volatile("v_permlane32_swap_b32 %0, %1" : "+v"(a), "+v"(b));
#endif
}
// global -> LDS direct (16B/lane). LDS dest: wave-uniform base + lane*16.
__device__ __forceinline__ void gload16(const void* g, void* l) {
    __builtin_amdgcn_global_load_lds(
        (const __attribute__((address_space(1))) unsigned int*)g,
        (__attribute__((address_space(3))) unsigned int*)l, 16, 0, 0);
}

// ---------- convert x f32 -> bf16 ----------
__global__ __launch_bounds__(256) void cvt_x(const float* __restrict__ in,
                                             u16* __restrict__ out) {
    int i = blockIdx.x * 256 + threadIdx.x;
    float4 v = reinterpret_cast<const float4*>(in)[i];
    ushort4 o;
    o.x = f2bf(v.x); o.y = f2bf(v.y); o.z = f2bf(v.z); o.w = f2bf(v.w);
    reinterpret_cast<ushort4*>(out)[i] = o;
}

// ---------- transpose+convert W [R][Ccols] f32 -> W^T [Ccols][R] bf16 ----------
__global__ __launch_bounds__(256) void wtrans(const float* __restrict__ in,
                                              u16* __restrict__ out,
                                              int R, int Ccols) {
    __shared__ float t[32][33];
    const int tx = threadIdx.x & 31, ty = threadIdx.x >> 5;  // 32x8
    const int bx = blockIdx.x, by = blockIdx.y;
    const int c = bx * 32 + tx;
#pragma unroll
    for (int j = 0; j < 4; ++j) {
        int r = by * 32 + ty + j * 8;
        t[ty + j * 8][tx] = in[(size_t)r * Ccols + c];
    }
    __syncthreads();
#pragma unroll
    for (int j = 0; j < 4; ++j) {
        int orow = bx * 32 + ty + j * 8;
        int oc   = by * 32 + tx;
        out[(size_t)orow * R + oc] = f2bf(t[tx][ty + j * 8]);
    }
}

// ---------- bf16 MFMA GEMM: C[M][N] = A[M][K] * BT[N][K]^T ----------
// m97 structure: 128x128 tile, 4 waves, 16x16x32 mfma, BK=32,
// global_load_lds width=16 into linear [128][32] LDS, 2-barrier loop.
template <int OUTF32>
__global__ __launch_bounds__(256) void gemm_mfma(const u16* __restrict__ A,
                                                 const u16* __restrict__ BT,
                                                 void* __restrict__ Cout,
                                                 int M, int N, int K) {
    __shared__ u16 As[128 * 32];
    __shared__ u16 Bs[128 * 32];
    const int tid = threadIdx.x;
    const int w = tid >> 6, l = tid & 63;
    const int wr = w >> 1, wc = w & 1;
    const int g = l >> 4, q = l & 15;
    const int bm = blockIdx.x * 128, bn = blockIdx.y * 128;
    const int lrow = l >> 2;          // 0..15 within a 16-row group
    const int lcol = (l & 3) * 8;     // u16 column within BK=32

    f32x4 acc[4][4] = {};
    const u16* Ap = A + (size_t)(bm + w * 32 + lrow) * K + lcol;
    const u16* Bp = BT + (size_t)(bn + w * 32 + lrow) * K + lcol;

    for (int k0 = 0; k0 < K; k0 += 32) {
        // wave w stages rows [w*32, w*32+32) of each tile: 2 calls x 16 rows
        gload16(Ap + k0, &As[(w * 32) * 32]);
        gload16(Ap + (size_t)16 * K + k0, &As[(w * 32 + 16) * 32]);
        gload16(Bp + k0, &Bs[(w * 32) * 32]);
        gload16(Bp + (size_t)16 * K + k0, &Bs[(w * 32 + 16) * 32]);
        __syncthreads();   // drains vmcnt -> LDS tiles ready
        short8v af[4], bf[4];
#pragma unroll
        for (int m = 0; m < 4; ++m)
            af[m] = *reinterpret_cast<const short8v*>(&As[(wr * 64 + m * 16 + q) * 32 + g * 8]);
#pragma unroll
        for (int n = 0; n < 4; ++n)
            bf[n] = *reinterpret_cast<const short8v*>(&Bs[(wc * 64 + n * 16 + q) * 32 + g * 8]);
#pragma unroll
        for (int m = 0; m < 4; ++m)
#pragma unroll
            for (int n = 0; n < 4; ++n)
                acc[m][n] = __builtin_amdgcn_mfma_f32_16x16x32_bf16(af[m], bf[n], acc[m][n], 0, 0, 0);
        __syncthreads();   // all waves done reading before next overwrite
    }

#pragma unroll
    for (int m = 0; m < 4; ++m)
#pragma unroll
        for (int n = 0; n < 4; ++n)
#pragma unroll
            for (int r = 0; r < 4; ++r) {
                int row = bm + wr * 64 + m * 16 + g * 4 + r;
                int col = bn + wc * 64 + n * 16 + q;
                if (OUTF32)
                    reinterpret_cast<float*>(Cout)[(size_t)row * N + col] = acc[m][n][r];
                else
                    reinterpret_cast<u16*>(Cout)[(size_t)row * N + col] = f2bf(acc[m][n][r]);
            }
}

// ---------- MFMA flash attention (causal), 32x32 structure ----------
// 4 waves x 32 q = 128 q per chunk; block does chunk pair (c, 15-c): uniform work.
// exp2-direct softmax with defer-max (T13), cvt_pk P-repack + permlane32_swap (T12).
__global__ __launch_bounds__(256) void attn_mfma(const u16* __restrict__ qkv,
                                                 u16* __restrict__ y) {
    __shared__ u16 SM[18432];   // 36,864 B: K dbuf 2x4608 | V^T dbuf 2x4608
    const int tid = threadIdx.x;
    const int w = tid >> 6, l = tid & 63;
    const int q31 = l & 31, hi = l >> 5;
    const int bid = blockIdx.x;
    const int bh = bid >> 3, c0 = bid & 7;
    const int b = bh >> 4, h = bh & 15;
    const size_t tok0 = (size_t)b * Tt;

    const float C2 = 0.18033688011112042f;   // 0.125 * log2(e)
    const float THR = 44.361419555836499f;   // 8 / C2  (defer-max threshold)

    // staging ids: 256 thr cover 64 keys x 8 d-segs (2 segs each)
    const int skey = tid >> 2;
    const int sseg = (tid & 3) * 2;
    const int kp = skey >> 1;          // V^T dword column
    const int veo = (skey & 1) * 4;    // e-range split by key parity

    for (int phase = 0; phase < 2; ++phase) {
        const int chunk = phase ? (15 - c0) : c0;
        const int nsteps = 2 * (chunk + 1);
        const int q0w = chunk * 128 + w * 32;
        const int qlane = q0w + q31;

        // Q fragments: B-operand, lane holds Q[q=l&31][d = 16s + 8hi + j]
        short8v qf0, qf1, qf2, qf3;
        {
            const u16* qp = qkv + (tok0 + qlane) * C3 + h * 64 + hi * 8;
            qf0 = *reinterpret_cast<const short8v*>(qp);
            qf1 = *reinterpret_cast<const short8v*>(qp + 16);
            qf2 = *reinterpret_cast<const short8v*>(qp + 32);
            qf3 = *reinterpret_cast<const short8v*>(qp + 48);
        }

        f32x16 acc0 = {}, acc1 = {};
        float m_run = -1e30f, l_run = 0.f;

        // ---- prologue: stage step 0 into buf 0 ----
        {
            const u16* gp = qkv + (tok0 + skey) * C3 + 1024 + h * 64 + sseg * 8;
            uint4 ka = *reinterpret_cast<const uint4*>(gp);
            uint4 kb = *reinterpret_cast<const uint4*>(gp + 8);
            uint4 va = *reinterpret_cast<const uint4*>(gp + 1024);
            uint4 vb = *reinterpret_cast<const uint4*>(gp + 1032);
            u16* Kd = SM;
            *reinterpret_cast<uint4*>(&Kd[skey * 72 + sseg * 8]) = ka;
            *reinterpret_cast<uint4*>(&Kd[skey * 72 + sseg * 8 + 8]) = kb;
            uint4 pa, pb;
            pa.x = __shfl_xor(va.x, 4); pa.y = __shfl_xor(va.y, 4);
            pa.z = __shfl_xor(va.z, 4); pa.w = __shfl_xor(va.w, 4);
            pb.x = __shfl_xor(vb.x, 4); pb.y = __shfl_xor(vb.y, 4);
            pb.z = __shfl_xor(vb.z, 4); pb.w = __shfl_xor(vb.w, 4);
            union UU { uint4 v; u16 hh[8]; };
            UU o0, o1, p0u, p1u;
            o0.v = va; o1.v = vb; p0u.v = pa; p1u.v = pb;
            unsigned int* Od = reinterpret_cast<unsigned int*>(SM + 9216);
#pragma unroll
            for (int i = 0; i < 4; ++i) {
                int e = veo + i;
                unsigned int w0 = (skey & 1)
                    ? ((unsigned)p0u.hh[e] | ((unsigned)o0.hh[e] << 16))
                    : ((unsigned)o0.hh[e] | ((unsigned)p0u.hh[e] << 16));
                unsigned int w1 = (skey & 1)
                    ? ((unsigned)p1u.hh[e] | ((unsigned)o1.hh[e] << 16))
                    : ((unsigned)o1.hh[e] | ((unsigned)p1u.hh[e] << 16));
                Od[(sseg * 8 + e) * 36 + kp] = w0;
                Od[(sseg * 8 + 8 + e) * 36 + kp] = w1;
            }
        }
        __syncthreads();

        for (int t = 0; t < nsteps; ++t) {
            const int cur = t & 1;
            const int k0 = t * 64;
            const bool pre = (t + 1 < nsteps);
            uint4 ka = {}, kb = {}, va = {}, vb = {};
            if (pre) {
                const u16* gp = qkv + (tok0 + (t + 1) * 64 + skey) * C3 + 1024 + h * 64 + sseg * 8;
                ka = *reinterpret_cast<const uint4*>(gp);
                kb = *reinterpret_cast<const uint4*>(gp + 8);
                va = *reinterpret_cast<const uint4*>(gp + 1024);
                vb = *reinterpret_cast<const uint4*>(gp + 1032);
            }

            if (k0 <= q0w + 31) {   // wave-uniform validity
                const u16* Kb = SM + cur * 4608;
                const u16* Vb = SM + 9216 + cur * 4608;
                // ---- S^T = K Q^T ----
                f32x16 st0 = {}, st1 = {};
#pragma unroll
                for (int s = 0; s < 4; ++s) {
                    short8v kfa = *reinterpret_cast<const short8v*>(&Kb[q31 * 72 + s * 16 + hi * 8]);
                    short8v kfb = *reinterpret_cast<const short8v*>(&Kb[(q31 + 32) * 72 + s * 16 + hi * 8]);
                    short8v qs = (s == 0) ? qf0 : (s == 1) ? qf1 : (s == 2) ? qf2 : qf3;
                    st0 = __builtin_amdgcn_mfma_f32_32x32x16_bf16(kfa, qs, st0, 0, 0, 0);
                    st1 = __builtin_amdgcn_mfma_f32_32x32x16_bf16(kfb, qs, st1, 0, 0, 0);
                }
                // ---- causal mask + row max (raw S units) ----
                const bool diag = (k0 + 63 > q0w);
                float s0[16], s1[16];
                float mx = -1e30f;
#pragma unroll
                for (int r = 0; r < 16; ++r) {
                    int krel = (r & 3) + 8 * (r >> 2) + 4 * hi;
                    float v0 = st0[r];
                    float v1 = st1[r];
                    if (diag) {
                        if (k0 + krel > qlane) v0 = -1e30f;
                        if (k0 + 32 + krel > qlane) v1 = -1e30f;
                    }
                    s0[r] = v0; s1[r] = v1;
                    mx = fmaxf(mx, fmaxf(v0, v1));
                }
                mx = fmaxf(mx, __shfl_xor(mx, 32));
                // ---- defer-max online softmax (exp2 space) ----
                if (!__all(mx <= m_run + THR)) {
                    float m_new = fmaxf(m_run, mx);
                    float alpha = exp2g((m_run - m_new) * C2);
                    l_run *= alpha;
                    acc0 *= alpha;
                    acc1 *= alpha;
                    m_run = m_new;
                }
                const float mc = m_run * C2;
                float rs = 0.f;
#pragma unroll
                for (int r = 0; r < 16; ++r) {
                    float p0 = exp2g(fmaf(s0[r], C2, -mc));
                    float p1 = exp2g(fmaf(s1[r], C2, -mc));
                    s0[r] = p0; s1[r] = p1;
                    rs += p0 + p1;
                }
                rs += __shfl_xor(rs, 32);
                l_run += rs;

                // ---- P -> bf16 B-frags via cvt_pk + permlane32_swap ----
                short8v pf0, pf1, pf2, pf3;
#define MKFRAG(dst, P, rb)                                                  \
                {                                                           \
                    unsigned int a_ = pk2(P[rb + 0], P[rb + 1]);            \
                    unsigned int b_ = pk2(P[rb + 4], P[rb + 5]);            \
                    unsigned int c_ = pk2(P[rb + 2], P[rb + 3]);            \
                    unsigned int d_ = pk2(P[rb + 6], P[rb + 7]);            \
                    plswap(a_, b_);                                         \
                    plswap(c_, d_);                                         \
                    union { unsigned int u[4]; short8v s; } uf_;            \
                    uf_.u[0] = a_; uf_.u[1] = c_; uf_.u[2] = b_; uf_.u[3] = d_; \
                    dst = uf_.s;                                            \
                }
                MKFRAG(pf0, s0, 0)
                MKFRAG(pf1, s0, 8)
                MKFRAG(pf2, s1, 0)
                MKFRAG(pf3, s1, 8)
#undef MKFRAG
                // ---- O^T += V^T P^T ----
#pragma unroll
                for (int s = 0; s < 4; ++s) {
                    short8v vfa = *reinterpret_cast<const short8v*>(&Vb[q31 * 72 + s * 16 + hi * 8]);
                    short8v vfb = *reinterpret_cast<const short8v*>(&Vb[(q31 + 32) * 72 + s * 16 + hi * 8]);
                    short8v ps = (s == 0) ? pf0 : (s == 1) ? pf1 : (s == 2) ? pf2 : pf3;
                    acc0 = __builtin_amdgcn_mfma_f32_32x32x16_bf16(vfa, ps, acc0, 0, 0, 0);
                    acc1 = __builtin_amdgcn_mfma_f32_32x32x16_bf16(vfb, ps, acc1, 0, 0, 0);
                }
            }

            if (pre) {
                u16* Kd = SM + (cur ^ 1) * 4608;
                *reinterpret_cast<uint4*>(&Kd[skey * 72 + sseg * 8]) = ka;
                *reinterpret_cast<uint4*>(&Kd[skey * 72 + sseg * 8 + 8]) = kb;
                uint4 pa, pb;
                pa.x = __shfl_xor(va.x, 4); pa.y = __shfl_xor(va.y, 4);
                pa.z = __shfl_xor(va.z, 4); pa.w = __shfl_xor(va.w, 4);
                pb.x = __shfl_xor(vb.x, 4); pb.y = __shfl_xor(vb.y, 4);
                pb.z = __shfl_xor(vb.z, 4); pb.w = __shfl_xor(vb.w, 4);
                union UU { uint4 v; u16 hh[8]; };
                UU o0, o1, p0u, p1u;
                o0.v = va; o1.v = vb; p0u.v = pa; p1u.v = pb;
                unsigned int* Od = reinterpret_cast<unsigned int*>(SM + 9216 + (cur ^ 1) * 4608);
#pragma unroll
                for (int i = 0; i < 4; ++i) {
                    int e = veo + i;
                    unsigned int w0 = (skey & 1)
                        ? ((unsigned)p0u.hh[e] | ((unsigned)o0.hh[e] << 16))
                        : ((unsigned)o0.hh[e] | ((unsigned)p0u.hh[e] << 16));
                    unsigned int w1 = (skey & 1)
                        ? ((unsigned)p1u.hh[e] | ((unsigned)o1.hh[e] << 16))
                        : ((unsigned)o1.hh[e] | ((unsigned)p1u.hh[e] << 16));
                    Od[(sseg * 8 + e) * 36 + kp] = w0;
                    Od[(sseg * 8 + 8 + e) * 36 + kp] = w1;
                }
            }
            __syncthreads();
        }

        // ---- store O: LDS transpose -> coalesced 16B stores ----
        const float inv = 1.f / l_run;
        unsigned int* Od2 = reinterpret_cast<unsigned int*>(SM);
        const int qrow = w * 32 + q31;
#pragma unroll
        for (int r = 0; r < 16; r += 2) {
            int d0 = (r & 3) + 8 * (r >> 2) + 4 * hi;   // even
            Od2[qrow * 36 + (d0 >> 1)] = pk2(acc0[r] * inv, acc0[r + 1] * inv);
            Od2[qrow * 36 + ((32 + d0) >> 1)] = pk2(acc1[r] * inv, acc1[r + 1] * inv);
        }
        __syncthreads();
        {
            const int row = w * 32 + (l >> 1);
            const int dh = (l & 1) * 32;
            const u16* src = SM + row * 72 + dh;
            u16* dst = y + (tok0 + chunk * 128 + row) * Cc + h * 64 + dh;
#pragma unroll
            for (int k2 = 0; k2 < 4; ++k2)
                *reinterpret_cast<uint4*>(dst + k2 * 8) =
                    *reinterpret_cast<const uint4*>(src + k2 * 8);
        }
        __syncthreads();   // protect SM before next phase's staging
    }
}

extern "C" void kernel_launch(void* const* d_in, const int* in_sizes, int n_in,
                              void* d_out, int out_size, void* d_ws, size_t ws_size,
                              hipStream_t stream) {
    const float* x    = (const float*)d_in[0];
    const float* Wqkv = (const float*)d_in[1];
    const float* Wout = (const float*)d_in[2];
    float* out = (float*)d_out;

    char* ws = (char*)d_ws;
    u16* qkv   = (u16*)(ws);
    u16* xbf   = (u16*)(ws + 50331648);  // aliased as y after GEMM1
    u16* WqkvT = (u16*)(ws + 67108864);
    u16* WoutT = (u16*)(ws + 73400320);

    cvt_x<<<(Mm * Cc) / (256 * 4), 256, 0, stream>>>(x, xbf);
    wtrans<<<dim3(C3 / 32, Cc / 32), 256, 0, stream>>>(Wqkv, WqkvT, Cc, C3);
    wtrans<<<dim3(Cc / 32, Cc / 32), 256, 0, stream>>>(Wout, WoutT, Cc, Cc);

    gemm_mfma<0><<<dim3(Mm / 128, C3 / 128), 256, 0, stream>>>(xbf, WqkvT, qkv, Mm, C3, Cc);

    u16* ybf = xbf;
    attn_mfma<<<512, 256, 0, stream>>>(qkv, ybf);

    gemm_mfma<1><<<dim3(Mm / 128, Cc / 128), 256, 0, stream>>>(ybf, WoutT, out, Mm, Cc, Cc);
}